// Round 6
// baseline (220.860 us; speedup 1.0000x reference)
//
#include <hip/hip_runtime.h>
#include <math.h>

#define NN 25000
#define NE 400000
#define TD 416
#define TCAP 46080             // per-type tlist/payload capacity (64-aligned)
#define NROWS (TCAP * 10)      // 460800 payload rows
#define PLH 64                 // payload row stride in halves (128 B = 2 lines)
#define GROWS 32

typedef __attribute__((ext_vector_type(8))) __bf16 bf16x8;
typedef __attribute__((ext_vector_type(4))) _Float16 f16x4;
typedef __attribute__((ext_vector_type(4))) float f32x4;

__device__ __forceinline__ float silu_f(float x) {
    return x * (1.0f / (1.0f + __expf(-x)));
}

// ---------- fused: [blocks 0..63] weight prep, [blocks 64..] count ----------
__global__ __launch_bounds__(256) void prep_count_k(
    const float* __restrict__ emb_table,
    const float* __restrict__ aw1, const float* __restrict__ ab1,
    const float* __restrict__ aw2, const float* __restrict__ ab2,
    const float* __restrict__ fw1, const float* __restrict__ fb1,
    const float* __restrict__ fw2,
    const float* __restrict__ fw3, const float* __restrict__ fb3,
    __bf16* __restrict__ w1a, __bf16* __restrict__ w2a,
    __bf16* __restrict__ w3ta, float* __restrict__ b3t,
    const int* __restrict__ esrc, const int* __restrict__ edst,
    const int* __restrict__ A,
    int* __restrict__ cnt_dst, int* __restrict__ cnt_t,
    int* __restrict__ rdst, int* __restrict__ rtp) {
    const int tid = threadIdx.x;
    if (blockIdx.x < 64) {
        __shared__ float s_ai[80];
        if (tid < 10) {
            float acc[8];
#pragma unroll
            for (int o = 0; o < 8; ++o) acc[o] = ab2[o];
            for (int j = 0; j < 64; ++j) {
                float h = ab1[j];
#pragma unroll
                for (int i = 0; i < 16; ++i) h += emb_table[tid * 16 + i] * aw1[i * 64 + j];
                h = silu_f(h);
#pragma unroll
                for (int o = 0; o < 8; ++o) acc[o] += h * aw2[j * 8 + o];
            }
#pragma unroll
            for (int o = 0; o < 8; ++o) s_ai[tid * 8 + o] = acc[o];
        }
        __syncthreads();
        for (int i = blockIdx.x * 256 + tid; i < 37344; i += 64 * 256) {
            if (i < 2048) {
                int m = i >> 9, r = i & 511, lane = r >> 3, j = r & 7;
                int k = (lane >> 4) * 8 + j, ch = m * 16 + (lane & 15);
                float v = (k < 8) ? fw1[k * 64 + ch] : ((k == 8) ? fb1[ch] : 0.0f);
                w1a[i] = (__bf16)v;
            } else if (i < 6144) {
                int q = i - 2048;
                int mk = q >> 9, lane = (q >> 3) & 63, j = q & 7;
                int m = mk >> 1, kt = mk & 1;
                int k = kt * 32 + (lane >> 4) * 8 + j, ch = m * 16 + (lane & 15);
                w2a[q] = (__bf16)fw2[k * 64 + ch];
            } else if (i < 36864) {
                int q = i - 6144;
                int tmk = q >> 9, lane = (q >> 3) & 63, j = q & 7;
                int kt = tmk & 1, tm = tmk >> 1;
                int t = tm / 3, m = tm - t * 3;
                int k = kt * 32 + (lane >> 4) * 8 + j, ch = m * 16 + (lane & 15);
                int l = ch >> 4, o = ch & 15;
                float s = 0.f;
#pragma unroll
                for (int c = 0; c < 8; ++c)
                    s += s_ai[t * 8 + c] * fw3[k * 384 + l * 128 + c * 16 + o];
                w3ta[q] = (__bf16)s;
            } else {
                int q2 = i - 36864;
                int t = q2 / 48, ch = q2 - t * 48;
                int l = ch >> 4, o = ch & 15;
                float s = 0.f;
#pragma unroll
                for (int c = 0; c < 8; ++c)
                    s += s_ai[t * 8 + c] * fb3[l * 128 + c * 16 + o];
                b3t[q2] = s;
            }
        }
    } else {
        __shared__ int lcnt[10];
        __shared__ int gbase[10];
        if (tid < 10) lcnt[tid] = 0;
        __syncthreads();
        int e = (blockIdx.x - 64) * 256 + tid;
        int t = 0, lr = 0;
        bool valid = e < NE;
        if (valid) {
            rdst[e] = atomicAdd(&cnt_dst[edst[e]], 1);
            t = A[esrc[e]];
            lr = atomicAdd(&lcnt[t], 1);
        }
        __syncthreads();
        if (tid < 10) gbase[tid] = atomicAdd(&cnt_t[tid], lcnt[tid]);
        __syncthreads();
        if (valid) rtp[e] = (t << 20) | (gbase[t] + lr);
    }
}

// ---------- alloc: CSR base per node via block scan + bump atomic (order-free) ----------
__global__ __launch_bounds__(256) void alloc_k(const int* __restrict__ cnt_dst,
                                               int* __restrict__ off_dst,
                                               int* __restrict__ bump) {
    __shared__ int s[256];
    __shared__ int sbase;
    const int tid = threadIdx.x;
    const int idx = blockIdx.x * 256 + tid;
    int c = (idx < NN) ? cnt_dst[idx] : 0;
    s[tid] = c;
    __syncthreads();
    for (int off = 1; off < 256; off <<= 1) {
        int v = (tid >= off) ? s[tid - off] : 0;
        __syncthreads();
        s[tid] += v;
        __syncthreads();
    }
    if (tid == 255) sbase = atomicAdd(bump, s[255]);
    __syncthreads();
    if (idx < NN) off_dst[idx] = sbase + s[tid] - c;
}

// ---------- scatter: tlist (type-bucketed edge ids) + elist (CSR of tlist positions) ----------
__global__ void scatter_k(const int* __restrict__ edst,
                          const int* __restrict__ off_dst,
                          const int* __restrict__ rdst, const int* __restrict__ rtp,
                          int* __restrict__ elist, int* __restrict__ tlist) {
    int e = blockIdx.x * blockDim.x + threadIdx.x;
    if (e >= NE) return;
    int rp = rtp[e];
    int p = (rp >> 20) * TCAP + (rp & 0xFFFFF);
    tlist[p] = e;
    elist[off_dst[edst[e]] + rdst[e]] = p;
}

// ---------- edge kernel: 1 wave = 64 edges; 3 MFMA GEMMs; direct coalesced stores ----------
__global__ __launch_bounds__(64) void edge_k(
    const int* __restrict__ tlist, const int* __restrict__ A,
    const int* __restrict__ esrc, const int* __restrict__ edst,
    const float* __restrict__ pos, const float* __restrict__ shifts,
    const float* __restrict__ cell, const int* __restrict__ batch,
    const __bf16* __restrict__ w1a, const __bf16* __restrict__ w2a,
    const __bf16* __restrict__ w3ta,
    const float* __restrict__ fb2, const float* __restrict__ b3t,
    _Float16* __restrict__ payload) {
    __shared__ __bf16 embuf[64 * 18];               // 2.3 KB (16 real halves/row)
    __shared__ __align__(16) __bf16 zbuf[16];       // shared zero K-block (quads 2,3)
    __shared__ __bf16 h1buf[16 * 72];               // 2.3 KB
    __shared__ __bf16 h2buf[16 * 72];               // 2.3 KB
    __shared__ float4 ubuf[64];                     // 1 KB
    const int lane = threadIdx.x;
    const int base = blockIdx.x * 64;
    const int e0 = tlist[base];
    if (e0 < 0) return;  // fully padded block (bucket fill is a 64-aligned prefix)
    int t_blk = __builtin_amdgcn_readfirstlane(A[esrc[e0]]);

    int eid = tlist[base + lane];
    if (eid < 0) eid = e0;  // pad lanes compute duplicate rows (never read)

    // ---- geometry ----
    const int src = esrc[eid], dstn = edst[eid];
    const int b = batch[src];
    const float* cb = cell + b * 9;
    const float sh0 = shifts[eid * 3 + 0], sh1 = shifts[eid * 3 + 1], sh2 = shifts[eid * 3 + 2];
    float vx = pos[dstn * 3 + 0] - pos[src * 3 + 0] + sh0 * cb[0] + sh1 * cb[3] + sh2 * cb[6];
    float vy = pos[dstn * 3 + 1] - pos[src * 3 + 1] + sh0 * cb[1] + sh1 * cb[4] + sh2 * cb[7];
    float vz = pos[dstn * 3 + 2] - pos[src * 3 + 2] + sh0 * cb[2] + sh1 * cb[5] + sh2 * cb[8];
    const float len = sqrtf(vx * vx + vy * vy + vz * vz + 1e-12f);
    const float il = 1.0f / len;
    ubuf[lane] = make_float4(vx * il, vy * il, vz * il, 0.f);

    // ---- radial basis row (16 halves; slot 8 = 1.0 folds bias; quads 2,3 read zbuf) ----
    bf16x8 er0;
#pragma unroll
    for (int k = 0; k < 8; ++k) {
        float d = (len - (5.0f * (float)(k + 1) / 9.0f)) * 1.8f;
        er0[k] = (__bf16)(__expf(-d * d) * 2.525381361380528f);  // sqrt(8)/1.12
    }
    bf16x8 er1 = {};
    er1[0] = (__bf16)1.0f;
    *(bf16x8*)&embuf[lane * 18 + 0] = er0;
    *(bf16x8*)&embuf[lane * 18 + 8] = er1;
    if (lane < 2) {
        bf16x8 zz = {};
        *(bf16x8*)&zbuf[lane * 8] = zz;
    }

    // ---- A-fragments (weights) + biases ----
    bf16x8 a1[4], a2[8], a3[6];
#pragma unroll
    for (int m = 0; m < 4; ++m) a1[m] = *(const bf16x8*)(w1a + (m * 64 + lane) * 8);
#pragma unroll
    for (int i = 0; i < 8; ++i) a2[i] = *(const bf16x8*)(w2a + (i * 64 + lane) * 8);
#pragma unroll
    for (int i = 0; i < 6; ++i)
        a3[i] = *(const bf16x8*)(w3ta + ((size_t)(t_blk * 6 + i) * 64 + lane) * 8);
    const int qr = (lane >> 4) * 4;
    const int q8 = (lane >> 4) * 8;
    f32x4 bias2[4], bias3[3];
#pragma unroll
    for (int m = 0; m < 4; ++m) bias2[m] = *(const f32x4*)(fb2 + m * 16 + qr);
#pragma unroll
    for (int m = 0; m < 3; ++m) bias3[m] = *(const f32x4*)(b3t + t_blk * 48 + m * 16 + qr);
    __syncthreads();

    const float SC = (float)NN / (float)NE;  // 1/16
    const int colrow = lane & 15;
#pragma unroll 1
    for (int n = 0; n < 4; ++n) {
        const int erow = n * 16 + colrow;
        // GEMM1: h1 = silu(emb @ W1 + b1)
        const __bf16* bp = (q8 < 16) ? &embuf[erow * 18 + q8] : &zbuf[q8 - 16];
        bf16x8 b1 = *(const bf16x8*)bp;
#pragma unroll
        for (int m = 0; m < 4; ++m) {
            f32x4 c = {0.f, 0.f, 0.f, 0.f};
            c = __builtin_amdgcn_mfma_f32_16x16x32_bf16(a1[m], b1, c, 0, 0, 0);
            __bf16 hp[4];
#pragma unroll
            for (int r = 0; r < 4; ++r) hp[r] = (__bf16)silu_f(c[r]);
            *(uint2*)&h1buf[colrow * 72 + m * 16 + qr] = *(uint2*)hp;
        }
        __syncthreads();
        // GEMM2: h2 = silu(h1 @ W2 + b2)
        bf16x8 b20 = *(bf16x8*)&h1buf[colrow * 72 + q8];
        bf16x8 b21 = *(bf16x8*)&h1buf[colrow * 72 + 32 + q8];
#pragma unroll
        for (int m = 0; m < 4; ++m) {
            f32x4 c = bias2[m];
            c = __builtin_amdgcn_mfma_f32_16x16x32_bf16(a2[m * 2 + 0], b20, c, 0, 0, 0);
            c = __builtin_amdgcn_mfma_f32_16x16x32_bf16(a2[m * 2 + 1], b21, c, 0, 0, 0);
            __bf16 hp[4];
#pragma unroll
            for (int r = 0; r < 4; ++r) hp[r] = (__bf16)silu_f(c[r]);
            *(uint2*)&h2buf[colrow * 72 + m * 16 + qr] = *(uint2*)hp;
        }
        __syncthreads();
        // GEMM3: s = (h2 @ W3t + b3t) * SC -> direct fp16 stores (16 rows x 32B sectors)
        bf16x8 b30 = *(bf16x8*)&h2buf[colrow * 72 + q8];
        bf16x8 b31 = *(bf16x8*)&h2buf[colrow * 72 + 32 + q8];
#pragma unroll
        for (int m = 0; m < 3; ++m) {
            f32x4 c = bias3[m];
            c = __builtin_amdgcn_mfma_f32_16x16x32_bf16(a3[m * 2 + 0], b30, c, 0, 0, 0);
            c = __builtin_amdgcn_mfma_f32_16x16x32_bf16(a3[m * 2 + 1], b31, c, 0, 0, 0);
            f16x4 hp;
#pragma unroll
            for (int r = 0; r < 4; ++r) hp[r] = (_Float16)(c[r] * SC);
            *(f16x4*)(payload + (size_t)(base + erow) * PLH + m * 16 + qr) = hp;
        }
        // row tail: u (3 x f32) + zero-fill -> completes both 64B lines this iteration
        if (lane >= 48) {
            int r = n * 16 + (lane - 48);
            float4 u = ubuf[r];
            _Float16* pr = payload + (size_t)(base + r) * PLH;
            *(uint4*)(pr + 48) = *(uint4*)&u;
            uint4 z4 = make_uint4(0, 0, 0, 0);
            *(uint4*)(pr + 56) = z4;
        }
        __syncthreads();
    }
}

// ---------- gather: elist-indirected 128B rows -> factor-table expansion -> out ----------
__global__ __launch_bounds__(256) void gather_k(const int* __restrict__ off_dst,
                                                const int* __restrict__ cnt_dst,
                                                const int* __restrict__ elist,
                                                const _Float16* __restrict__ payload,
                                                float* __restrict__ out) {
    __shared__ int spid[GROWS];
    __shared__ __align__(16) _Float16 sp_s[GROWS][72];
    __shared__ float sfac[GROWS][16];
    const int n = blockIdx.x;
    const int tid = threadIdx.x;
    const int lo = off_dst[n];
    const int cnt = cnt_dst[n];
    int voff = 0, foff = 0;
    if (tid < 16) { voff = tid; foff = 0; }
    else if (tid < 64) { int q = tid - 16; voff = 16 + q / 3; foff = 1 + q % 3; }
    else if (tid < 208) { int q = tid - 64; voff = 32 + q / 9; foff = 4 + q % 9; }
    float acc = 0.f;
    for (int p0 = 0; p0 < cnt; p0 += GROWS) {
        const int m = min(GROWS, cnt - p0);
        if (tid < m) spid[tid] = elist[lo + p0 + tid];
        __syncthreads();
        if (tid < m * 8) {
            int r = tid >> 3, q = tid & 7;
            ((uint4*)&sp_s[r][0])[q] = ((const uint4*)(payload + (size_t)spid[r] * PLH))[q];
        }
        __syncthreads();
        for (int idx = tid; idx < m * 16; idx += 256) {
            int r = idx >> 4, f = idx & 15;
            if (f < 13) {
                const float* uf = (const float*)&sp_s[r][48];
                float v;
                if (f == 0) v = 1.0f;
                else if (f < 4) v = uf[f - 1];
                else { int g = f - 4; v = uf[g / 3] * uf[g % 3]; }
                sfac[r][f] = v;
            }
        }
        __syncthreads();
        if (tid < 208)
            for (int r = 0; r < m; ++r)
                acc += (float)sp_s[r][voff] * sfac[r][foff];
        __syncthreads();
    }
    if (tid < 208) {
        out[(size_t)n * TD + tid] = acc;
        out[(size_t)n * TD + 208 + tid] = 0.f;
    }
}

extern "C" void kernel_launch(void* const* d_in, const int* in_sizes, int n_in,
                              void* d_out, int out_size, void* d_ws, size_t ws_size,
                              hipStream_t stream) {
    const float* pos       = (const float*)d_in[0];
    const int*   A         = (const int*)d_in[1];
    const int*   batch     = (const int*)d_in[2];
    const int*   esrc      = (const int*)d_in[3];
    const int*   edst      = (const int*)d_in[4];
    const float* shifts    = (const float*)d_in[5];
    const float* cell      = (const float*)d_in[6];
    const float* emb_table = (const float*)d_in[7];
    const float* aw1       = (const float*)d_in[8];
    const float* ab1       = (const float*)d_in[9];
    const float* aw2       = (const float*)d_in[10];
    const float* ab2       = (const float*)d_in[11];
    const float* fw1       = (const float*)d_in[12];
    const float* fb1       = (const float*)d_in[13];
    const float* fw2       = (const float*)d_in[14];
    const float* fb2       = (const float*)d_in[15];
    const float* fw3       = (const float*)d_in[16];
    const float* fb3       = (const float*)d_in[17];
    float* out = (float*)d_out;

    // ---- ws layout (bytes from base) ----
    char* base = (char*)d_ws;
    __bf16* w1a    = (__bf16*)(base + 0);        // 4096 B
    __bf16* w2a    = (__bf16*)(base + 4096);     // 8192 B
    __bf16* w3ta   = (__bf16*)(base + 12288);    // 61440 B
    float*  b3t    = (float*)(base + 73728);     // 1920 B -> ends 75648
    int* cnt_dst   = (int*)(base + 75648);       // 25008*4 -> 175680
    int* cnt_t     = (int*)(base + 175680);      // 64 B
    int* bump      = (int*)(base + 175744);      // 64 B
    int* off_dst   = (int*)(base + 175808);      // 25008*4 -> 275840
    int* rdst      = (int*)(base + 275840);      // 1.6 MB
    int* rtp       = (int*)(base + 1875840);     // 1.6 MB
    int* elist     = (int*)(base + 3475840);     // 1.6 MB
    int* tlist     = (int*)(base + 5075840);     // 460800*4 = 1843200 -> 6919040
    _Float16* payload = (_Float16*)(base + 6919168);  // 460800*128 B = 59.0 MB

    hipMemsetAsync(cnt_dst, 0, 100160, stream);        // cnt_dst + cnt_t + bump
    hipMemsetAsync(tlist, 0xFF, NROWS * 4, stream);    // bucket pads = -1
    prep_count_k<<<64 + (NE + 255) / 256, 256, 0, stream>>>(
        emb_table, aw1, ab1, aw2, ab2, fw1, fb1, fw2, fw3, fb3,
        w1a, w2a, w3ta, b3t, esrc, edst, A, cnt_dst, cnt_t, rdst, rtp);
    alloc_k<<<(NN + 255) / 256, 256, 0, stream>>>(cnt_dst, off_dst, bump);
    scatter_k<<<(NE + 255) / 256, 256, 0, stream>>>(edst, off_dst, rdst, rtp, elist, tlist);
    edge_k<<<NROWS / 64, 64, 0, stream>>>(tlist, A, esrc, edst, pos, shifts, cell, batch,
                                          w1a, w2a, w3ta, fb2, b3t, payload);
    gather_k<<<NN, 256, 0, stream>>>(off_dst, cnt_dst, elist, payload, out);
}